// Round 1
// baseline (442.706 us; speedup 1.0000x reference)
//
#include <hip/hip_runtime.h>
#include <hip/hip_bf16.h>

#define NB   4
#define MD   2048
#define KD   2048
#define ND   2048
#define BM   128
#define BN   128
#define BK   32
#define LSTR 40   // BK + 8 pad: 80B row = 16B-aligned for ds_read_b128, 20-bank step

typedef short bf16x8 __attribute__((ext_vector_type(8)));
typedef float f32x4  __attribute__((ext_vector_type(4)));

__device__ __forceinline__ unsigned short f2bf(float x) {
    union { float f; unsigned u; } v; v.f = x;
    unsigned r = v.u + 0x7FFFu + ((v.u >> 16) & 1u);   // round-to-nearest-even
    return (unsigned short)(r >> 16);
}

__global__ __launch_bounds__(256) void SparseMatmul_kernel(
    const float* __restrict__ A, const float* __restrict__ Bmat,
    float* __restrict__ C)
{
    __shared__ unsigned short As[BM][LSTR];   // [m][k], k contiguous
    __shared__ unsigned short Bs[BN][LSTR];   // [n][k], k contiguous (transposed)

    const int tid   = threadIdx.x;
    const int batch = blockIdx.z;
    const int row0  = blockIdx.y * BM;
    const int col0  = blockIdx.x * BN;

    const float* Abase = A    + (size_t)batch * MD * KD + (size_t)row0 * KD;
    const float* Bbase = Bmat + (size_t)batch * KD * ND + col0;
    float*       Cbase = C    + (size_t)batch * MD * ND + (size_t)row0 * ND + col0;

    // staging coordinates (256 threads cover 128x32 A-floats and 32x128 B-floats, 4 float4 each)
    const int a_row = tid >> 3;          // 0..31, +32 per i
    const int a_kc  = (tid & 7) * 4;     // k offset within BK
    const int b_kk  = tid >> 5;          // 0..7, +8 per i
    const int b_n   = (tid & 31) * 4;    // n offset within BN

    const int wave = tid >> 6;
    const int lane = tid & 63;
    const int q    = lane >> 4;          // quad 0..3
    const int r    = lane & 15;
    const int wm   = (wave >> 1) * 64;   // wave 2x2 grid over 128x128
    const int wn   = (wave & 1)  * 64;

    f32x4 acc[4][4];
    #pragma unroll
    for (int i = 0; i < 4; ++i)
        #pragma unroll
        for (int j = 0; j < 4; ++j)
            acc[i][j] = (f32x4){0.f, 0.f, 0.f, 0.f};

    for (int k0 = 0; k0 < KD; k0 += BK) {
        // ---- stage A tile: fp32 -> bf16, layout As[m][k] ----
        #pragma unroll
        for (int i = 0; i < 4; ++i) {
            const int row = a_row + i * 32;
            const float4 v = *(const float4*)(Abase + (size_t)row * KD + k0 + a_kc);
            ushort4 w;
            w.x = f2bf(v.x); w.y = f2bf(v.y); w.z = f2bf(v.z); w.w = f2bf(v.w);
            *(ushort4*)&As[row][a_kc] = w;   // ds_write_b64
        }
        // ---- stage B tile transposed: Bs[n][k] ----
        #pragma unroll
        for (int i = 0; i < 4; ++i) {
            const int kk = b_kk + i * 8;
            const float4 v = *(const float4*)(Bbase + (size_t)(k0 + kk) * ND + b_n);
            Bs[b_n + 0][kk] = f2bf(v.x);
            Bs[b_n + 1][kk] = f2bf(v.y);
            Bs[b_n + 2][kk] = f2bf(v.z);
            Bs[b_n + 3][kk] = f2bf(v.w);
        }
        __syncthreads();

        // ---- fragments + MFMA ----
        bf16x8 a_frag[4], b_frag[4];
        #pragma unroll
        for (int im = 0; im < 4; ++im)
            a_frag[im] = *(const bf16x8*)&As[wm + im * 16 + r][q * 8];   // ds_read_b128
        #pragma unroll
        for (int in = 0; in < 4; ++in)
            b_frag[in] = *(const bf16x8*)&Bs[wn + in * 16 + r][q * 8];

        #pragma unroll
        for (int im = 0; im < 4; ++im)
            #pragma unroll
            for (int in = 0; in < 4; ++in)
                acc[im][in] = __builtin_amdgcn_mfma_f32_16x16x32_bf16(
                    a_frag[im], b_frag[in], acc[im][in], 0, 0, 0);

        __syncthreads();
    }

    // ---- epilogue: C/D layout col=lane&15, row=quad*4+reg (m89-verified) ----
    #pragma unroll
    for (int im = 0; im < 4; ++im)
        #pragma unroll
        for (int in = 0; in < 4; ++in)
            #pragma unroll
            for (int j = 0; j < 4; ++j) {
                const int row = wm + im * 16 + q * 4 + j;
                const int col = wn + in * 16 + r;
                Cbase[(size_t)row * ND + col] = acc[im][in][j];
            }
}

extern "C" void kernel_launch(void* const* d_in, const int* in_sizes, int n_in,
                              void* d_out, int out_size, void* d_ws, size_t ws_size,
                              hipStream_t stream) {
    const float* a = (const float*)d_in[0];
    const float* b = (const float*)d_in[1];
    float* out = (float*)d_out;
    dim3 grid(ND / BN, MD / BM, NB);   // 16 x 16 x 4 = 1024 blocks
    SparseMatmul_kernel<<<grid, dim3(256), 0, stream>>>(a, b, out);
}

// Round 2
// 279.737 us; speedup vs baseline: 1.5826x; 1.5826x over previous
//
#include <hip/hip_runtime.h>
#include <hip/hip_bf16.h>

#define NB   4
#define MD   2048
#define KD   2048
#define ND   2048
#define BM   128
#define BN   128
#define BK   32
#define LSTR 40   // BK + 8 pad: 80B row = 16B-aligned for ds_read_b128; stride 20 dwords

typedef short bf16x8 __attribute__((ext_vector_type(8)));
typedef float f32x4  __attribute__((ext_vector_type(4)));

// pack two fp32 -> one dword of 2 bf16 (RNE); uses hw v_cvt_pk_bf16_f32 if available
__device__ __forceinline__ unsigned pk2(float lo, float hi) {
    union { __hip_bfloat162 h2; unsigned u; } c;
    c.h2 = __float22bfloat162_rn(make_float2(lo, hi));
    return c.u;
}

__global__ __launch_bounds__(256, 4) void SparseMatmul_kernel(
    const float* __restrict__ A, const float* __restrict__ Bmat,
    float* __restrict__ C)
{
    __shared__ unsigned short As[BM][LSTR];   // [m][k], k contiguous
    __shared__ unsigned short Bs[BN][LSTR];   // [n][k], k contiguous (transposed)

    const int tid   = threadIdx.x;
    const int batch = blockIdx.z;
    const int row0  = blockIdx.y * BM;
    const int col0  = blockIdx.x * BN;

    const float* Abase = A    + (size_t)batch * MD * KD + (size_t)row0 * KD;
    const float* Bbase = Bmat + (size_t)batch * KD * ND + col0;
    float*       Cbase = C    + (size_t)batch * MD * ND + (size_t)row0 * ND + col0;

    // A staging: 8 threads per row, float4 each, 4 row-groups
    const int a_row = tid >> 3;          // 0..31, +32 per i
    const int a_kc  = (tid & 7) * 4;     // k offset within BK

    // B staging: thread owns column n, 16 consecutive k (2 passes of 8)
    const int b_n  = tid & 127;          // column within tile
    const int b_kh = (tid >> 7) * 16;    // k base within BK
    const float* Bcol = Bbase + b_n;

    const int wave = tid >> 6;
    const int lane = tid & 63;
    const int q    = lane >> 4;          // quad 0..3
    const int r    = lane & 15;
    const int wm   = (wave >> 1) * 64;   // wave 2x2 grid over 128x128
    const int wn   = (wave & 1)  * 64;

    f32x4 acc[4][4];
    #pragma unroll
    for (int i = 0; i < 4; ++i)
        #pragma unroll
        for (int j = 0; j < 4; ++j)
            acc[i][j] = (f32x4){0.f, 0.f, 0.f, 0.f};

    for (int k0 = 0; k0 < KD; k0 += BK) {
        // ---- stage A tile: fp32 -> bf16, As[m][k], b64 writes (conflict-optimal) ----
        #pragma unroll
        for (int i = 0; i < 4; ++i) {
            const int row = a_row + i * 32;
            const float4 v = *(const float4*)(Abase + (size_t)row * KD + k0 + a_kc);
            uint2 w;
            w.x = pk2(v.x, v.y);
            w.y = pk2(v.z, v.w);
            *(uint2*)&As[row][a_kc] = w;
        }
        // ---- stage B tile transposed: Bs[n][k], 2 passes of 8 k, b128 writes ----
        #pragma unroll
        for (int h = 0; h < 2; ++h) {
            const int kb = b_kh + h * 8;
            float bv[8];
            #pragma unroll
            for (int j = 0; j < 8; ++j)
                bv[j] = Bcol[(size_t)(k0 + kb + j) * ND];   // coalesced per wave
            uint4 w;
            w.x = pk2(bv[0], bv[1]);
            w.y = pk2(bv[2], bv[3]);
            w.z = pk2(bv[4], bv[5]);
            w.w = pk2(bv[6], bv[7]);
            *(uint4*)&Bs[b_n][kb] = w;   // 16B-aligned: 80*n + 2*kb, kb in {0,8,16,24}
        }
        __syncthreads();

        // ---- fragments + MFMA ----
        bf16x8 a_frag[4], b_frag[4];
        #pragma unroll
        for (int im = 0; im < 4; ++im)
            a_frag[im] = *(const bf16x8*)&As[wm + im * 16 + r][q * 8];   // ds_read_b128
        #pragma unroll
        for (int in = 0; in < 4; ++in)
            b_frag[in] = *(const bf16x8*)&Bs[wn + in * 16 + r][q * 8];

        #pragma unroll
        for (int im = 0; im < 4; ++im)
            #pragma unroll
            for (int in = 0; in < 4; ++in)
                acc[im][in] = __builtin_amdgcn_mfma_f32_16x16x32_bf16(
                    a_frag[im], b_frag[in], acc[im][in], 0, 0, 0);

        __syncthreads();
    }

    // ---- epilogue: C/D layout col=lane&15, row=quad*4+reg (m89-verified) ----
    #pragma unroll
    for (int im = 0; im < 4; ++im)
        #pragma unroll
        for (int in = 0; in < 4; ++in)
            #pragma unroll
            for (int j = 0; j < 4; ++j) {
                const int row = wm + im * 16 + q * 4 + j;
                const int col = wn + in * 16 + r;
                Cbase[(size_t)row * ND + col] = acc[im][in][j];
            }
}

extern "C" void kernel_launch(void* const* d_in, const int* in_sizes, int n_in,
                              void* d_out, int out_size, void* d_ws, size_t ws_size,
                              hipStream_t stream) {
    const float* a = (const float*)d_in[0];
    const float* b = (const float*)d_in[1];
    float* out = (float*)d_out;
    dim3 grid(ND / BN, MD / BM, NB);   // 16 x 16 x 4 = 1024 blocks
    SparseMatmul_kernel<<<grid, dim3(256), 0, stream>>>(a, b, out);
}